// Round 16
// baseline (167.847 us; speedup 1.0000x reference)
//
#include <hip/hip_runtime.h>

typedef unsigned int u32;
typedef unsigned short u16;
typedef __attribute__((ext_vector_type(8))) short bf16x8;
typedef __attribute__((ext_vector_type(4))) float f32x4;

// ---------------- helpers ----------------
__device__ __forceinline__ u32 f2bf(float f) {
  u32 x = __float_as_uint(f);
  return (x + 0x7fffu + ((x >> 16) & 1u)) >> 16;   // RNE to bf16 bits
}
__device__ __forceinline__ float bf2f(u16 u) {
  return __uint_as_float(((u32)u) << 16);
}
__device__ __forceinline__ void addbf8(float* a, uint4 v) {
  a[0] += bf2f((u16)v.x); a[1] += bf2f((u16)(v.x >> 16));
  a[2] += bf2f((u16)v.y); a[3] += bf2f((u16)(v.y >> 16));
  a[4] += bf2f((u16)v.z); a[5] += bf2f((u16)(v.z >> 16));
  a[6] += bf2f((u16)v.w); a[7] += bf2f((u16)(v.w >> 16));
}

// ---------------- setup: zero cnt + prep both weight buffers ----------------
// G layout (u16): G[c*128 + (k ^ ((c&7)<<3))] = bf16(W[k][c]), c in [0,256):
//   c<128 -> Wl col c ; c>=128 -> Wr col (c-128). Linear LDS copy -> swizzled tile.
__global__ void setup_kernel(const float* __restrict__ Wl1, const float* __restrict__ Wr1,
                             const float* __restrict__ Wl2, const float* __restrict__ Wr2,
                             u16* __restrict__ G1, u16* __restrict__ G2,
                             int* __restrict__ cnt, int n) {
  int b = blockIdx.x;
  if (b < 256) {
    const float* Wl = (b < 128) ? Wl1 : Wl2;
    const float* Wr = (b < 128) ? Wr1 : Wr2;
    u16* G = (b < 128) ? G1 : G2;
    int id = (b & 127) * 256 + threadIdx.x;       // 0..32767
    int c = id >> 7;
    int k = id & 127;
    const float* W = (c < 128) ? Wl : Wr;
    float v = W[k * 128 + (c & 127)];
    G[c * 128 + (k ^ ((c & 7) << 3))] = (u16)f2bf(v);
  } else {
    int i = (b - 256) * 256 + threadIdx.x;
    if (i < n) cnt[i] = 0;
  }
}

// ---------------- CSR build ----------------
// hist: count in-degree AND record each edge's within-node slot (atomic ret val)
__global__ void hist_kernel(const int* __restrict__ dst, int* __restrict__ cnt,
                            int* __restrict__ pos, int E) {
  int e = blockIdx.x * blockDim.x + threadIdx.x;
  if (e < E) pos[e] = atomicAdd(&cnt[dst[e]], 1);
}

#define SCAN_CHUNK 2048

__global__ __launch_bounds__(256) void scan_sums(const int* __restrict__ cnt,
                                                 int* __restrict__ bsum, int n) {
  __shared__ int red[256];
  int t = threadIdx.x;
  int base = blockIdx.x * SCAN_CHUNK + t * 8;
  int s = 0;
#pragma unroll
  for (int i = 0; i < 8; ++i) {
    int idx = base + i;
    if (idx < n) s += cnt[idx];
  }
  red[t] = s;
  __syncthreads();
  for (int off = 128; off > 0; off >>= 1) {
    if (t < off) red[t] += red[t + off];
    __syncthreads();
  }
  if (t == 0) bsum[blockIdx.x] = red[0];
}

// scan_apply: each block locally ex-scans the (<=32) raw block partials,
// then does its 2048-elem chunk. Block 0 also writes row_ptr[n] = E.
__global__ __launch_bounds__(256) void scan_apply(
    const int* __restrict__ cnt, const int* __restrict__ bsum, int nb,
    int* __restrict__ row_ptr, float* __restrict__ inv_cnt, int n) {
  __shared__ int sc[256];
  __shared__ int base_s;
  int t = threadIdx.x;
  if (t == 0) {
    int run = 0;
    int bid = blockIdx.x;
    int base = 0;
    for (int i = 0; i < nb; ++i) {
      if (i == bid) base = run;
      run += bsum[i];
    }
    base_s = base;
    if (bid == 0) row_ptr[n] = run;   // E
  }
  int chunk_base = blockIdx.x * SCAN_CHUNK + t * 8;
  int v[8];
  int s = 0;
#pragma unroll
  for (int i = 0; i < 8; ++i) {
    int idx = chunk_base + i;
    v[i] = (idx < n) ? cnt[idx] : 0;
    s += v[i];
  }
  sc[t] = s;
  __syncthreads();
  for (int off = 1; off < 256; off <<= 1) {
    int add = (t >= off) ? sc[t - off] : 0;
    __syncthreads();
    sc[t] += add;
    __syncthreads();
  }
  int run = base_s + ((t > 0) ? sc[t - 1] : 0);
#pragma unroll
  for (int i = 0; i < 8; ++i) {
    int idx = chunk_base + i;
    if (idx < n) {
      row_ptr[idx] = run;
      inv_cnt[idx] = 1.0f / (float)max(v[i], 1);
      run += v[i];
    }
  }
}

// ------ dual-GEMM (r8-proven): stage B once, 2x 64-row tiles, LDS epilogue ------
template <int IN_BF16>
__device__ __forceinline__ void gemm_tiles(const void* in_, const u16* __restrict__ G,
                                           const float* __restrict__ bias,
                                           u16* __restrict__ yl, u16* __restrict__ yr,
                                           int n, uint4* lds4, int gb) {
  char* As = (char*)lds4;                      // [0, 16KB) — A tile, then C staging
  char* Bt = (char*)lds4 + 16384;              // [16KB, 80KB)
  const int t = threadIdx.x;
  const int lane = t & 63;
  const int wave = t >> 6;
  const int wr = wave >> 1;
  const int wc = wave & 1;
  const int lhi = lane >> 4;
  const int llo = lane & 15;

  // stage B once (linear copy; G pre-swizzled)
  {
    const uint4* gbp = (const uint4*)G;
    uint4* lb = lds4 + 1024;
#pragma unroll
    for (int i = 0; i < 16; ++i) lb[i * 256 + t] = gbp[i * 256 + t];
  }

  const int ntiles = (n + 63) / 64;
#pragma unroll 1
  for (int tile = gb * 2; tile < ntiles && tile < gb * 2 + 2; ++tile) {
    const int row0 = tile * 64;
    __syncthreads();   // B visible (iter0) / prev-iter C-stage reads done
    // stage A: 64 rows x 128 elems -> bf16, swizzled 16B granules
#pragma unroll
    for (int i = 0; i < 4; ++i) {
      int g = t + i * 256;
      int r = g >> 4;
      int gc = g & 15;
      int row = row0 + r;
      uint4 pk = {0u, 0u, 0u, 0u};
      if (row < n) {
        if (IN_BF16) {
          pk = *(const uint4*)((const u16*)in_ + (size_t)row * 128 + gc * 8);
        } else {
          const float4* pp = (const float4*)((const float*)in_ + (size_t)row * 128 + gc * 8);
          float4 v0 = pp[0], v1 = pp[1];
          pk.x = f2bf(v0.x) | (f2bf(v0.y) << 16);
          pk.y = f2bf(v0.z) | (f2bf(v0.w) << 16);
          pk.z = f2bf(v1.x) | (f2bf(v1.y) << 16);
          pk.w = f2bf(v1.z) | (f2bf(v1.w) << 16);
        }
      }
      *(uint4*)(As + r * 256 + ((gc * 16) ^ ((r & 7) << 4))) = pk;
    }
    __syncthreads();

    f32x4 acc[2][8];
#pragma unroll
    for (int fr = 0; fr < 2; ++fr)
#pragma unroll
      for (int fc = 0; fc < 8; ++fc) acc[fr][fc] = {0.f, 0.f, 0.f, 0.f};

#pragma unroll
    for (int ks = 0; ks < 4; ++ks) {
      const int kbyte = ks * 64 + lhi * 16;
      bf16x8 a[2], bb[8];
#pragma unroll
      for (int fr = 0; fr < 2; ++fr) {
        int r = wr * 32 + fr * 16 + llo;
        a[fr] = *(const bf16x8*)(As + r * 256 + (kbyte ^ ((r & 7) << 4)));
      }
#pragma unroll
      for (int fc = 0; fc < 8; ++fc) {
        int c = wc * 128 + fc * 16 + llo;
        bb[fc] = *(const bf16x8*)(Bt + c * 256 + (kbyte ^ ((c & 7) << 4)));
      }
#pragma unroll
      for (int fr = 0; fr < 2; ++fr)
#pragma unroll
        for (int fc = 0; fc < 8; ++fc)
          acc[fr][fc] = __builtin_amdgcn_mfma_f32_16x16x32_bf16(a[fr], bb[fc], acc[fr][fc], 0, 0, 0);
    }

    // epilogue: C layout col=lane&15, row=(lane>>4)*4+i (m89-verified)
#pragma unroll 1
    for (int ph = 0; ph < 2; ++ph) {
      __syncthreads();
      if (wc == ph) {
#pragma unroll
        for (int fc = 0; fc < 8; ++fc) {
          int cc = fc * 16 + llo;
          float bv = (ph == 1) ? bias[cc] : 0.0f;
#pragma unroll
          for (int fr = 0; fr < 2; ++fr) {
#pragma unroll
            for (int i = 0; i < 4; ++i) {
              int row = wr * 32 + fr * 16 + lhi * 4 + i;
              *(u16*)(As + row * 256 + ((cc * 2) ^ (lhi << 5))) =
                  (u16)f2bf(acc[fr][fc][i] + bv);
            }
          }
        }
      }
      __syncthreads();
      u16* outp = (ph == 0) ? yl : yr;
#pragma unroll
      for (int j = 0; j < 4; ++j) {
        int idx = t + j * 256;
        int row = idx >> 4;
        int cb = (idx & 15) * 16;
        int grow = row0 + row;
        if (grow < n) {
          uint4 v = *(const uint4*)(As + row * 256 + (cb ^ (((row >> 2) & 3) << 5)));
          *(uint4*)((char*)(outp + (size_t)grow * 128) + cb) = v;
        }
      }
    }
  }
}

// ---- fused: blocks [0,GB) gemm layer-1; [GB,GB+FB) atomic-free CSR fill ----
// fill: position = row_ptr[dst] + pos (recorded by hist). 2048 edges/block, 8-deep.
__global__ __launch_bounds__(256, 2) void gemm1_fill_kernel(
    const float* __restrict__ x, const u16* __restrict__ G1, const float* __restrict__ b1,
    u16* __restrict__ yl, u16* __restrict__ yr, int n,
    const int* __restrict__ src, const int* __restrict__ dst,
    const int* __restrict__ pos, const int* __restrict__ row_ptr,
    int* __restrict__ colv, int E, int GB) {
  __shared__ uint4 lds4[5120];                 // 80 KB
  if ((int)blockIdx.x < GB) {
    gemm_tiles<0>(x, G1, b1, yl, yr, n, lds4, blockIdx.x);
  } else {
    int base = ((int)blockIdx.x - GB) * 2048 + threadIdx.x;
    int dd[8], pp[8], ss[8], rp[8];
#pragma unroll
    for (int j = 0; j < 8; ++j) {
      int e = base + j * 256;
      if (e < E) { dd[j] = dst[e]; pp[j] = pos[e]; ss[j] = src[e]; }
    }
#pragma unroll
    for (int j = 0; j < 8; ++j) {
      int e = base + j * 256;
      if (e < E) rp[j] = row_ptr[dd[j]];
    }
#pragma unroll
    for (int j = 0; j < 8; ++j) {
      int e = base + j * 256;
      if (e < E) colv[rp[j] + pp[j]] = ss[j];
    }
  }
}

template <int IN_BF16>
__global__ __launch_bounds__(256, 2) void gemm_kernel(
    const void* __restrict__ in_, const u16* __restrict__ G, const float* __restrict__ bias,
    u16* __restrict__ yl, u16* __restrict__ yr, int n) {
  __shared__ uint4 lds4[5120];                 // 80 KB
  gemm_tiles<IN_BF16>(in_, G, bias, yl, yr, n, lds4, blockIdx.x);
}

// ------- L2-blocked aggregation: out = relu?(invc * sum_nb(yl) + yr) -------
// Column-quartered: quarter q covers cols q*32..q*32+31 (64 B/row = cache-line
// granularity). Quarter-major grid -> active yl slice ~3.2 MB, fits per-XCD L2.
// Node per 4-lane group (64 nodes/block); 8-deep predicated gather.
template <int RELU, int OUT_BF16>
__global__ __launch_bounds__(256) void agg_kernel(
    const u16* __restrict__ yl, const u16* __restrict__ yr,
    const int* __restrict__ row_ptr, const int* __restrict__ colv,
    const float* __restrict__ invc, void* __restrict__ out_, int n, int nb) {
  int q = blockIdx.x / nb;            // quarter 0..3 (quarter-major dispatch)
  int nblk = blockIdx.x - q * nb;
  int node = nblk * 64 + (threadIdx.x >> 2);
  if (node >= n) return;
  int l4 = threadIdx.x & 3;
  int co = q * 32 + l4 * 8;           // this lane's 8 cols
  const u16* ylq = yl + co;
  int beg = row_ptr[node], end = row_ptr[node + 1];
  uint4 rv = *(const uint4*)(yr + (size_t)node * 128 + co);  // early
  float s = invc[node];
  float a[8] = {0.f, 0.f, 0.f, 0.f, 0.f, 0.f, 0.f, 0.f};
  for (int e0 = beg; e0 < end; e0 += 8) {
    int m = end - e0;
    if (m > 8) m = 8;
    uint4 v0, v1, v2, v3, v4, v5, v6, v7;
    if (0 < m) v0 = *(const uint4*)(ylq + (size_t)colv[e0 + 0] * 128);
    if (1 < m) v1 = *(const uint4*)(ylq + (size_t)colv[e0 + 1] * 128);
    if (2 < m) v2 = *(const uint4*)(ylq + (size_t)colv[e0 + 2] * 128);
    if (3 < m) v3 = *(const uint4*)(ylq + (size_t)colv[e0 + 3] * 128);
    if (4 < m) v4 = *(const uint4*)(ylq + (size_t)colv[e0 + 4] * 128);
    if (5 < m) v5 = *(const uint4*)(ylq + (size_t)colv[e0 + 5] * 128);
    if (6 < m) v6 = *(const uint4*)(ylq + (size_t)colv[e0 + 6] * 128);
    if (7 < m) v7 = *(const uint4*)(ylq + (size_t)colv[e0 + 7] * 128);
    if (0 < m) addbf8(a, v0);
    if (1 < m) addbf8(a, v1);
    if (2 < m) addbf8(a, v2);
    if (3 < m) addbf8(a, v3);
    if (4 < m) addbf8(a, v4);
    if (5 < m) addbf8(a, v5);
    if (6 < m) addbf8(a, v6);
    if (7 < m) addbf8(a, v7);
  }
  float r[8];
  r[0] = bf2f((u16)rv.x); r[1] = bf2f((u16)(rv.x >> 16));
  r[2] = bf2f((u16)rv.y); r[3] = bf2f((u16)(rv.y >> 16));
  r[4] = bf2f((u16)rv.z); r[5] = bf2f((u16)(rv.z >> 16));
  r[6] = bf2f((u16)rv.w); r[7] = bf2f((u16)(rv.w >> 16));
  float o[8];
#pragma unroll
  for (int j = 0; j < 8; ++j) {
    o[j] = a[j] * s + r[j];
    if (RELU) o[j] = fmaxf(o[j], 0.f);
  }
  if (OUT_BF16) {
    uint4 pk;
    pk.x = f2bf(o[0]) | (f2bf(o[1]) << 16);
    pk.y = f2bf(o[2]) | (f2bf(o[3]) << 16);
    pk.z = f2bf(o[4]) | (f2bf(o[5]) << 16);
    pk.w = f2bf(o[6]) | (f2bf(o[7]) << 16);
    *(uint4*)((u16*)out_ + (size_t)node * 128 + co) = pk;
  } else {
    float4 q0 = {o[0], o[1], o[2], o[3]};
    float4 q1 = {o[4], o[5], o[6], o[7]};
    float* op = (float*)out_ + (size_t)node * 128 + co;
    *(float4*)op = q0;
    *(float4*)(op + 4) = q1;
  }
}

// ---------------- launch ----------------
extern "C" void kernel_launch(void* const* d_in, const int* in_sizes, int n_in,
                              void* d_out, int out_size, void* d_ws, size_t ws_size,
                              hipStream_t stream) {
  const float* x = (const float*)d_in[0];
  const int* ei = (const int*)d_in[1];
  const float* Wl1 = (const float*)d_in[2];
  const float* Wr1 = (const float*)d_in[3];
  const float* b1 = (const float*)d_in[4];
  const float* Wl2 = (const float*)d_in[5];
  const float* Wr2 = (const float*)d_in[6];
  const float* b2 = (const float*)d_in[7];

  const int N = in_sizes[0] / 128;
  const int E = in_sizes[1] / 2;
  const int* srcv = ei;
  const int* dstv = ei + E;

  char* ws = (char*)d_ws;
  u16* yl = (u16*)ws;       ws += (size_t)N * 128 * 2;   // GEMM left output (bf16)
  u16* yr = (u16*)ws;       ws += (size_t)N * 128 * 2;   // GEMM right output (bf16)
  u16* hbf = (u16*)ws;      ws += (size_t)N * 128 * 2;   // layer-1 activations (bf16)
  u16* G1 = (u16*)ws;       ws += 256 * 128 * 2;
  u16* G2 = (u16*)ws;       ws += 256 * 128 * 2;
  int* colv = (int*)ws;     ws += (size_t)E * 4;
  int* pos = (int*)ws;      ws += (size_t)E * 4;
  int* row_ptr = (int*)ws;  ws += ((size_t)N + 64) * 4;
  int* cnt = (int*)ws;      ws += (size_t)N * 4;
  float* invc = (float*)ws; ws += (size_t)N * 4;
  int* bsum = (int*)ws;     ws += 256 * 4;

  const int nsb = (N + SCAN_CHUNK - 1) / SCAN_CHUNK;
  const int ntiles = (N + 63) / 64;
  const int GB = (ntiles + 1) / 2;             // 2 tiles per gemm block
  const int FB = (E + 2047) / 2048;            // 2048 edges per fill block
  const int nbq = (N + 63) / 64;               // agg node-blocks per quarter

  setup_kernel<<<256 + (N + 255) / 256, 256, 0, stream>>>(Wl1, Wr1, Wl2, Wr2, G1, G2, cnt, N);
  hist_kernel<<<(E + 255) / 256, 256, 0, stream>>>(dstv, cnt, pos, E);
  scan_sums<<<nsb, 256, 0, stream>>>(cnt, bsum, N);
  scan_apply<<<nsb, 256, 0, stream>>>(cnt, bsum, nsb, row_ptr, invc, N);
  gemm1_fill_kernel<<<GB + FB, 256, 0, stream>>>(x, G1, b1, yl, yr, N,
                                                 srcv, dstv, pos, row_ptr, colv, E, GB);
  agg_kernel<1, 1><<<4 * nbq, 256, 0, stream>>>(yl, yr, row_ptr, colv, invc, hbf, N, nbq);
  gemm_kernel<1><<<GB, 256, 0, stream>>>(hbf, G2, b2, yl, yr, N);
  agg_kernel<0, 0><<<4 * nbq, 256, 0, stream>>>(yl, yr, row_ptr, colv, invc, d_out, N, nbq);
}

// Round 17
// 139.115 us; speedup vs baseline: 1.2065x; 1.2065x over previous
//
#include <hip/hip_runtime.h>

typedef unsigned int u32;
typedef unsigned short u16;
typedef __attribute__((ext_vector_type(8))) short bf16x8;
typedef __attribute__((ext_vector_type(4))) float f32x4;

// ---------------- helpers ----------------
__device__ __forceinline__ u32 f2bf(float f) {
  u32 x = __float_as_uint(f);
  return (x + 0x7fffu + ((x >> 16) & 1u)) >> 16;   // RNE to bf16 bits
}
__device__ __forceinline__ float bf2f(u16 u) {
  return __uint_as_float(((u32)u) << 16);
}
__device__ __forceinline__ void addbf8(float* a, uint4 v) {
  a[0] += bf2f((u16)v.x); a[1] += bf2f((u16)(v.x >> 16));
  a[2] += bf2f((u16)v.y); a[3] += bf2f((u16)(v.y >> 16));
  a[4] += bf2f((u16)v.z); a[5] += bf2f((u16)(v.z >> 16));
  a[6] += bf2f((u16)v.w); a[7] += bf2f((u16)(v.w >> 16));
}

// ---------------- setup: zero cnt + prep both weight buffers ----------------
// G layout (u16): G[c*128 + (k ^ ((c&7)<<3))] = bf16(W[k][c]), c in [0,256):
//   c<128 -> Wl col c ; c>=128 -> Wr col (c-128). Linear LDS copy -> swizzled tile.
__global__ void setup_kernel(const float* __restrict__ Wl1, const float* __restrict__ Wr1,
                             const float* __restrict__ Wl2, const float* __restrict__ Wr2,
                             u16* __restrict__ G1, u16* __restrict__ G2,
                             int* __restrict__ cnt, int n) {
  int b = blockIdx.x;
  if (b < 256) {
    const float* Wl = (b < 128) ? Wl1 : Wl2;
    const float* Wr = (b < 128) ? Wr1 : Wr2;
    u16* G = (b < 128) ? G1 : G2;
    int id = (b & 127) * 256 + threadIdx.x;       // 0..32767
    int c = id >> 7;
    int k = id & 127;
    const float* W = (c < 128) ? Wl : Wr;
    float v = W[k * 128 + (c & 127)];
    G[c * 128 + (k ^ ((c & 7) << 3))] = (u16)f2bf(v);
  } else {
    int i = (b - 256) * 256 + threadIdx.x;
    if (i < n) cnt[i] = 0;
  }
}

// ---------------- CSR build ----------------
// hist: count in-degree AND record each edge's within-node slot (atomic ret val)
__global__ void hist_kernel(const int* __restrict__ dst, int* __restrict__ cnt,
                            int* __restrict__ pos, int E) {
  int e = blockIdx.x * blockDim.x + threadIdx.x;
  if (e < E) pos[e] = atomicAdd(&cnt[dst[e]], 1);
}

#define SCAN_CHUNK 2048

__global__ __launch_bounds__(256) void scan_sums(const int* __restrict__ cnt,
                                                 int* __restrict__ bsum, int n) {
  __shared__ int red[256];
  int t = threadIdx.x;
  int base = blockIdx.x * SCAN_CHUNK + t * 8;
  int s = 0;
#pragma unroll
  for (int i = 0; i < 8; ++i) {
    int idx = base + i;
    if (idx < n) s += cnt[idx];
  }
  red[t] = s;
  __syncthreads();
  for (int off = 128; off > 0; off >>= 1) {
    if (t < off) red[t] += red[t + off];
    __syncthreads();
  }
  if (t == 0) bsum[blockIdx.x] = red[0];
}

// scan_apply: each block locally ex-scans the (<=32) raw block partials,
// then does its 2048-elem chunk. Block 0 also writes row_ptr[n] = E.
__global__ __launch_bounds__(256) void scan_apply(
    const int* __restrict__ cnt, const int* __restrict__ bsum, int nb,
    int* __restrict__ row_ptr, float* __restrict__ inv_cnt, int n) {
  __shared__ int sc[256];
  __shared__ int base_s;
  int t = threadIdx.x;
  if (t == 0) {
    int run = 0;
    int bid = blockIdx.x;
    int base = 0;
    for (int i = 0; i < nb; ++i) {
      if (i == bid) base = run;
      run += bsum[i];
    }
    base_s = base;
    if (bid == 0) row_ptr[n] = run;   // E
  }
  int chunk_base = blockIdx.x * SCAN_CHUNK + t * 8;
  int v[8];
  int s = 0;
#pragma unroll
  for (int i = 0; i < 8; ++i) {
    int idx = chunk_base + i;
    v[i] = (idx < n) ? cnt[idx] : 0;
    s += v[i];
  }
  sc[t] = s;
  __syncthreads();
  for (int off = 1; off < 256; off <<= 1) {
    int add = (t >= off) ? sc[t - off] : 0;
    __syncthreads();
    sc[t] += add;
    __syncthreads();
  }
  int run = base_s + ((t > 0) ? sc[t - 1] : 0);
#pragma unroll
  for (int i = 0; i < 8; ++i) {
    int idx = chunk_base + i;
    if (idx < n) {
      row_ptr[idx] = run;
      inv_cnt[idx] = 1.0f / (float)max(v[i], 1);
      run += v[i];
    }
  }
}

// ------ dual-GEMM (r8-proven) + global_load_lds staging ------
// B-stage: 64KB linear copy via direct-to-LDS async loads (width=16).
// A-stage: IN_BF16=1 -> global_load_lds with pre-swizzled SOURCE address
// (LDS stays linear; swizzle moved to the global address per m173);
// IN_BF16=0 -> VALU convert path (fp32->bf16 needs registers).
template <int IN_BF16>
__device__ __forceinline__ void gemm_tiles(const void* in_, const u16* __restrict__ G,
                                           const float* __restrict__ bias,
                                           u16* __restrict__ yl, u16* __restrict__ yr,
                                           int n, uint4* lds4, int gb) {
  char* As = (char*)lds4;                      // [0, 16KB) — A tile, then C staging
  char* Bt = (char*)lds4 + 16384;              // [16KB, 80KB)
  const int t = threadIdx.x;
  const int lane = t & 63;
  const int wave = t >> 6;
  const int wr = wave >> 1;
  const int wc = wave & 1;
  const int lhi = lane >> 4;
  const int llo = lane & 15;

  // stage B once: direct-to-LDS (linear; G pre-swizzled). Loads remain in
  // flight until the first __syncthreads (which drains vmcnt).
  {
    const char* gbp = (const char*)G;
#pragma unroll
    for (int i = 0; i < 16; ++i) {
      int g = i * 256 + t;
      __builtin_amdgcn_global_load_lds((const u32*)(gbp + g * 16),
                                       (u32*)(Bt + g * 16), 16, 0, 0);
    }
  }

  const int ntiles = (n + 63) / 64;
#pragma unroll 1
  for (int tile = gb * 2; tile < ntiles && tile < gb * 2 + 2; ++tile) {
    const int row0 = tile * 64;
    __syncthreads();   // B visible (iter0) / prev-iter C-stage reads done
    // stage A: 64 rows x 128 elems -> bf16 tile, swizzled 16B granules
#pragma unroll
    for (int i = 0; i < 4; ++i) {
      int g = t + i * 256;                     // LDS granule 0..1023
      int r = g >> 4;
      int gcl = g & 15;
      int row = row0 + r;
      if (IN_BF16) {
        if (row < n) {
          // source granule pre-swizzled: LDS stays linear, addr carries XOR
          int gcs = gcl ^ (r & 7);
          __builtin_amdgcn_global_load_lds(
              (const u32*)((const u16*)in_ + (size_t)row * 128 + gcs * 8),
              (u32*)(As + g * 16), 16, 0, 0);
        } else {
          uint4 z = {0u, 0u, 0u, 0u};
          *(uint4*)(As + g * 16) = z;
        }
      } else {
        uint4 pk = {0u, 0u, 0u, 0u};
        if (row < n) {
          const float4* pp = (const float4*)((const float*)in_ + (size_t)row * 128 + gcl * 8);
          float4 v0 = pp[0], v1 = pp[1];
          pk.x = f2bf(v0.x) | (f2bf(v0.y) << 16);
          pk.y = f2bf(v0.z) | (f2bf(v0.w) << 16);
          pk.z = f2bf(v1.x) | (f2bf(v1.y) << 16);
          pk.w = f2bf(v1.z) | (f2bf(v1.w) << 16);
        }
        *(uint4*)(As + r * 256 + ((gcl * 16) ^ ((r & 7) << 4))) = pk;
      }
    }
    __syncthreads();

    f32x4 acc[2][8];
#pragma unroll
    for (int fr = 0; fr < 2; ++fr)
#pragma unroll
      for (int fc = 0; fc < 8; ++fc) acc[fr][fc] = {0.f, 0.f, 0.f, 0.f};

#pragma unroll
    for (int ks = 0; ks < 4; ++ks) {
      const int kbyte = ks * 64 + lhi * 16;
      bf16x8 a[2], bb[8];
#pragma unroll
      for (int fr = 0; fr < 2; ++fr) {
        int r = wr * 32 + fr * 16 + llo;
        a[fr] = *(const bf16x8*)(As + r * 256 + (kbyte ^ ((r & 7) << 4)));
      }
#pragma unroll
      for (int fc = 0; fc < 8; ++fc) {
        int c = wc * 128 + fc * 16 + llo;
        bb[fc] = *(const bf16x8*)(Bt + c * 256 + (kbyte ^ ((c & 7) << 4)));
      }
#pragma unroll
      for (int fr = 0; fr < 2; ++fr)
#pragma unroll
        for (int fc = 0; fc < 8; ++fc)
          acc[fr][fc] = __builtin_amdgcn_mfma_f32_16x16x32_bf16(a[fr], bb[fc], acc[fr][fc], 0, 0, 0);
    }

    // epilogue: C layout col=lane&15, row=(lane>>4)*4+i (m89-verified)
#pragma unroll 1
    for (int ph = 0; ph < 2; ++ph) {
      __syncthreads();
      if (wc == ph) {
#pragma unroll
        for (int fc = 0; fc < 8; ++fc) {
          int cc = fc * 16 + llo;
          float bv = (ph == 1) ? bias[cc] : 0.0f;
#pragma unroll
          for (int fr = 0; fr < 2; ++fr) {
#pragma unroll
            for (int i = 0; i < 4; ++i) {
              int row = wr * 32 + fr * 16 + lhi * 4 + i;
              *(u16*)(As + row * 256 + ((cc * 2) ^ (lhi << 5))) =
                  (u16)f2bf(acc[fr][fc][i] + bv);
            }
          }
        }
      }
      __syncthreads();
      u16* outp = (ph == 0) ? yl : yr;
#pragma unroll
      for (int j = 0; j < 4; ++j) {
        int idx = t + j * 256;
        int row = idx >> 4;
        int cb = (idx & 15) * 16;
        int grow = row0 + row;
        if (grow < n) {
          uint4 v = *(const uint4*)(As + row * 256 + (cb ^ (((row >> 2) & 3) << 5)));
          *(uint4*)((char*)(outp + (size_t)grow * 128) + cb) = v;
        }
      }
    }
  }
}

// ---- fused: blocks [0,GB) gemm layer-1; [GB,GB+FB) atomic-free CSR fill ----
// fill: position = row_ptr[dst] + pos (recorded by hist). 2048 edges/block, 8-deep.
__global__ __launch_bounds__(256, 2) void gemm1_fill_kernel(
    const float* __restrict__ x, const u16* __restrict__ G1, const float* __restrict__ b1,
    u16* __restrict__ yl, u16* __restrict__ yr, int n,
    const int* __restrict__ src, const int* __restrict__ dst,
    const int* __restrict__ pos, const int* __restrict__ row_ptr,
    int* __restrict__ colv, int E, int GB) {
  __shared__ uint4 lds4[5120];                 // 80 KB
  if ((int)blockIdx.x < GB) {
    gemm_tiles<0>(x, G1, b1, yl, yr, n, lds4, blockIdx.x);
  } else {
    int base = ((int)blockIdx.x - GB) * 2048 + threadIdx.x;
    int dd[8], pp[8], ss[8], rp[8];
#pragma unroll
    for (int j = 0; j < 8; ++j) {
      int e = base + j * 256;
      if (e < E) { dd[j] = dst[e]; pp[j] = pos[e]; ss[j] = src[e]; }
    }
#pragma unroll
    for (int j = 0; j < 8; ++j) {
      int e = base + j * 256;
      if (e < E) rp[j] = row_ptr[dd[j]];
    }
#pragma unroll
    for (int j = 0; j < 8; ++j) {
      int e = base + j * 256;
      if (e < E) colv[rp[j] + pp[j]] = ss[j];
    }
  }
}

template <int IN_BF16>
__global__ __launch_bounds__(256, 2) void gemm_kernel(
    const void* __restrict__ in_, const u16* __restrict__ G, const float* __restrict__ bias,
    u16* __restrict__ yl, u16* __restrict__ yr, int n) {
  __shared__ uint4 lds4[5120];                 // 80 KB
  gemm_tiles<IN_BF16>(in_, G, bias, yl, yr, n, lds4, blockIdx.x);
}

// ------- aggregation (r15-proven): out = relu?(invc * sum_nb(yl) + yr) -------
// One node per 16-lane group (uint4 = 8 bf16/lane); 8-deep predicated gather.
template <int RELU, int OUT_BF16>
__global__ __launch_bounds__(256) void agg_kernel(
    const u16* __restrict__ yl, const u16* __restrict__ yr,
    const int* __restrict__ row_ptr, const int* __restrict__ colv,
    const float* __restrict__ invc, void* __restrict__ out_, int n) {
  int node = blockIdx.x * 16 + (threadIdx.x >> 4);
  if (node >= n) return;
  int sl = threadIdx.x & 15;
  int beg = row_ptr[node], end = row_ptr[node + 1];
  uint4 rv = *(const uint4*)(yr + (size_t)node * 128 + sl * 8);  // early
  float s = invc[node];
  float a[8] = {0.f, 0.f, 0.f, 0.f, 0.f, 0.f, 0.f, 0.f};
  for (int e0 = beg; e0 < end; e0 += 8) {
    int m = end - e0;
    if (m > 8) m = 8;
    uint4 v0, v1, v2, v3, v4, v5, v6, v7;
    if (0 < m) v0 = *(const uint4*)(yl + (size_t)colv[e0 + 0] * 128 + sl * 8);
    if (1 < m) v1 = *(const uint4*)(yl + (size_t)colv[e0 + 1] * 128 + sl * 8);
    if (2 < m) v2 = *(const uint4*)(yl + (size_t)colv[e0 + 2] * 128 + sl * 8);
    if (3 < m) v3 = *(const uint4*)(yl + (size_t)colv[e0 + 3] * 128 + sl * 8);
    if (4 < m) v4 = *(const uint4*)(yl + (size_t)colv[e0 + 4] * 128 + sl * 8);
    if (5 < m) v5 = *(const uint4*)(yl + (size_t)colv[e0 + 5] * 128 + sl * 8);
    if (6 < m) v6 = *(const uint4*)(yl + (size_t)colv[e0 + 6] * 128 + sl * 8);
    if (7 < m) v7 = *(const uint4*)(yl + (size_t)colv[e0 + 7] * 128 + sl * 8);
    if (0 < m) addbf8(a, v0);
    if (1 < m) addbf8(a, v1);
    if (2 < m) addbf8(a, v2);
    if (3 < m) addbf8(a, v3);
    if (4 < m) addbf8(a, v4);
    if (5 < m) addbf8(a, v5);
    if (6 < m) addbf8(a, v6);
    if (7 < m) addbf8(a, v7);
  }
  float r[8];
  r[0] = bf2f((u16)rv.x); r[1] = bf2f((u16)(rv.x >> 16));
  r[2] = bf2f((u16)rv.y); r[3] = bf2f((u16)(rv.y >> 16));
  r[4] = bf2f((u16)rv.z); r[5] = bf2f((u16)(rv.z >> 16));
  r[6] = bf2f((u16)rv.w); r[7] = bf2f((u16)(rv.w >> 16));
  float o[8];
#pragma unroll
  for (int j = 0; j < 8; ++j) {
    o[j] = a[j] * s + r[j];
    if (RELU) o[j] = fmaxf(o[j], 0.f);
  }
  if (OUT_BF16) {
    uint4 pk;
    pk.x = f2bf(o[0]) | (f2bf(o[1]) << 16);
    pk.y = f2bf(o[2]) | (f2bf(o[3]) << 16);
    pk.z = f2bf(o[4]) | (f2bf(o[5]) << 16);
    pk.w = f2bf(o[6]) | (f2bf(o[7]) << 16);
    *(uint4*)((u16*)out_ + (size_t)node * 128 + sl * 8) = pk;
  } else {
    float4 q0 = {o[0], o[1], o[2], o[3]};
    float4 q1 = {o[4], o[5], o[6], o[7]};
    float* op = (float*)out_ + (size_t)node * 128 + sl * 8;
    *(float4*)op = q0;
    *(float4*)(op + 4) = q1;
  }
}

// ---------------- launch ----------------
extern "C" void kernel_launch(void* const* d_in, const int* in_sizes, int n_in,
                              void* d_out, int out_size, void* d_ws, size_t ws_size,
                              hipStream_t stream) {
  const float* x = (const float*)d_in[0];
  const int* ei = (const int*)d_in[1];
  const float* Wl1 = (const float*)d_in[2];
  const float* Wr1 = (const float*)d_in[3];
  const float* b1 = (const float*)d_in[4];
  const float* Wl2 = (const float*)d_in[5];
  const float* Wr2 = (const float*)d_in[6];
  const float* b2 = (const float*)d_in[7];

  const int N = in_sizes[0] / 128;
  const int E = in_sizes[1] / 2;
  const int* srcv = ei;
  const int* dstv = ei + E;

  char* ws = (char*)d_ws;
  u16* yl = (u16*)ws;       ws += (size_t)N * 128 * 2;   // GEMM left output (bf16)
  u16* yr = (u16*)ws;       ws += (size_t)N * 128 * 2;   // GEMM right output (bf16)
  u16* hbf = (u16*)ws;      ws += (size_t)N * 128 * 2;   // layer-1 activations (bf16)
  u16* G1 = (u16*)ws;       ws += 256 * 128 * 2;
  u16* G2 = (u16*)ws;       ws += 256 * 128 * 2;
  int* colv = (int*)ws;     ws += (size_t)E * 4;
  int* pos = (int*)ws;      ws += (size_t)E * 4;
  int* row_ptr = (int*)ws;  ws += ((size_t)N + 64) * 4;
  int* cnt = (int*)ws;      ws += (size_t)N * 4;
  float* invc = (float*)ws; ws += (size_t)N * 4;
  int* bsum = (int*)ws;     ws += 256 * 4;

  const int nsb = (N + SCAN_CHUNK - 1) / SCAN_CHUNK;
  const int ntiles = (N + 63) / 64;
  const int GB = (ntiles + 1) / 2;             // 2 tiles per gemm block
  const int FB = (E + 2047) / 2048;            // 2048 edges per fill block

  setup_kernel<<<256 + (N + 255) / 256, 256, 0, stream>>>(Wl1, Wr1, Wl2, Wr2, G1, G2, cnt, N);
  hist_kernel<<<(E + 255) / 256, 256, 0, stream>>>(dstv, cnt, pos, E);
  scan_sums<<<nsb, 256, 0, stream>>>(cnt, bsum, N);
  scan_apply<<<nsb, 256, 0, stream>>>(cnt, bsum, nsb, row_ptr, invc, N);
  gemm1_fill_kernel<<<GB + FB, 256, 0, stream>>>(x, G1, b1, yl, yr, N,
                                                 srcv, dstv, pos, row_ptr, colv, E, GB);
  agg_kernel<1, 1><<<(N + 15) / 16, 256, 0, stream>>>(yl, yr, row_ptr, colv, invc, hbf, N);
  gemm_kernel<1><<<GB, 256, 0, stream>>>(hbf, G2, b2, yl, yr, N);
  agg_kernel<0, 0><<<(N + 15) / 16, 256, 0, stream>>>(yl, yr, row_ptr, colv, invc, d_out, N);
}